// Round 6
// baseline (4649.688 us; speedup 1.0000x reference)
//
#include <hip/hip_runtime.h>

// LSTM forward, B=32 T=1024 D=512 U=512, fp32.
// Persistent fused kernel, 256 WGs x 512 thr (all co-resident, grid == #CUs).
// Group g = blockIdx&7 handles batches 4g..4g+3; WG w = blockIdx>>3 owns
// 16 units (64 gate columns). Weights in VGPRs: waves 0-3 hold R-slices
// (critical path), waves 4-7 hold K-slices (xz pipeline).
//
// R6: slice-local dataflow on the critical path.
//  - crit wave wv polls ONLY units [128*wv,128*wv+128) x 4 batches of h(t-1)
//    (its own dot inputs), stages them into its private LH slice, lgkmcnt,
//    and dots immediately -- NO cross-wave barrier before the dot. Each wave
//    starts when ITS 8 producer WGs have landed (overlaps arrival spread).
//  - LR is parity double-buffered (LR[t&1]): dot(t+2) can only overwrite
//    gates(t)'s parity after B2(t+1), which waits for wave0, which passed
//    gates(t) -- provably race-free with just the per-step B2.
//  - xz waves free-run RDEPTH ahead into an LDS ring (R5 structure), their
//    barrier spins now s_sleep to stay off the LDS/issue ports.
//  - sync mechanism: R4-proven sentinel data-poll (RELAXED+AGENT, LLC).
// d_out doubles as h history; memset to 0xFFFFFFFF (sentinel) per launch.

#define TT 1024
#define DD 512
#define UU 512
#define NCOL 2048
#define SENT 0xFFFFFFFFu
#define RDEPTH 4

__device__ __forceinline__ float hsig(float v) {
  return fminf(fmaxf(0.2f * v + 0.5f, 0.0f), 1.0f);
}
__device__ __forceinline__ float tanh_fast(float x) {
  float e = __expf(2.0f * x);
  return 1.0f - 2.0f / (e + 1.0f);
}

// 64-k dot, column-pair, 4 batch streams. W[2j],W[2j+1] = weights of the two
// columns for k-index j. Sources may be LDS (h) or global (x); float4 reads.
__device__ __forceinline__ void dot64x2_4(
    const float* p0, const float* p1, const float* p2, const float* p3,
    const float (&W)[128],
    float& a00, float& a01, float& a10, float& a11,
    float& a20, float& a21, float& a30, float& a31) {
  a00 = a01 = a10 = a11 = a20 = a21 = a30 = a31 = 0.f;
#pragma unroll
  for (int j4 = 0; j4 < 16; ++j4) {
    float4 v0 = *(const float4*)(p0 + j4 * 4);
    float4 v1 = *(const float4*)(p1 + j4 * 4);
    float4 v2 = *(const float4*)(p2 + j4 * 4);
    float4 v3 = *(const float4*)(p3 + j4 * 4);
    const float* e0 = (const float*)&v0;
    const float* e1 = (const float*)&v1;
    const float* e2 = (const float*)&v2;
    const float* e3 = (const float*)&v3;
#pragma unroll
    for (int jj = 0; jj < 4; ++jj) {
      float w0 = W[2 * (4 * j4 + jj) + 0];
      float w1 = W[2 * (4 * j4 + jj) + 1];
      a00 += e0[jj] * w0; a01 += e0[jj] * w1;
      a10 += e1[jj] * w0; a11 += e1[jj] * w1;
      a20 += e2[jj] * w0; a21 += e2[jj] * w1;
      a30 += e3[jj] * w0; a31 += e3[jj] * w1;
    }
  }
}

// Epoch barrier for the 4 waves of one half (waves 0-3 or 4-7).
template <bool SLEEP>
__device__ __forceinline__ void wavebar(int* ctr, int& ep) {
  asm volatile("s_waitcnt lgkmcnt(0)" ::: "memory");  // prior LDS writes done
  if ((threadIdx.x & 63) == 0)
    __hip_atomic_fetch_add(ctr, 1, __ATOMIC_RELAXED, __HIP_MEMORY_SCOPE_WORKGROUP);
  ep += 4;
  while (__hip_atomic_load(ctr, __ATOMIC_RELAXED, __HIP_MEMORY_SCOPE_WORKGROUP) < ep) {
    if (SLEEP) __builtin_amdgcn_s_sleep(1);
  }
  asm volatile("" ::: "memory");
}

__global__ __launch_bounds__(512, 2) void lstm_persistent(
    const float* __restrict__ x,
    const float* __restrict__ Wk,
    const float* __restrict__ Wr,
    const float* __restrict__ bias,
    float* __restrict__ out) {
  const int tid = (int)threadIdx.x;
  const int g   = (int)blockIdx.x & 7;
  const int w   = (int)blockIdx.x >> 3;
  const bool crit = (tid < 256);
  const int idx = tid & 255;
  const int o   = idx >> 5;        // k-octant
  const int col0 = (idx & 31) * 2; // local column pair
  const int gcol = ((col0 >> 4) * UU) + w * 16 + (col0 & 15);

  const float* M = crit ? Wr : Wk;
  float W[128];
#pragma unroll
  for (int j = 0; j < 64; ++j) {
    float2 ww = *(const float2*)(M + (size_t)(o * 64 + j) * NCOL + gcol);
    W[2 * j] = ww.x; W[2 * j + 1] = ww.y;
  }

  __shared__ float LX[8][4][65];        // xz partials
  __shared__ float LR[2][8][4][65];     // recurrent partials, parity by t
  __shared__ float RING[RDEPTH][4][66]; // reduced xz ring
  __shared__ float LH[4][512];          // h(t-1) staged (per-wave slices)
  __shared__ float LB[64];              // bias slice
  __shared__ int cXZdone, cCRITdone, cXZbar, cCRITbar;

  if (tid == 0) { cXZdone = 0; cCRITdone = 0; cXZbar = 0; cCRITbar = 0; }
  if (tid < 64) LB[tid] = bias[(tid >> 4) * UU + w * 16 + (tid & 15)];
  __syncthreads();  // one-time init barrier only

  if (crit) {
    // ---------------- critical pipeline: waves 0-3 ----------------
    const int wv = tid >> 6;   // crit wave id 0..3; owns units [128wv,128wv+128)
    const int l  = tid & 63;
    const unsigned* ou0 = (const unsigned*)out + (size_t)(g * 4 + 0) * TT * UU;
    const unsigned* ou1 = (const unsigned*)out + (size_t)(g * 4 + 1) * TT * UU;
    const unsigned* ou2 = (const unsigned*)out + (size_t)(g * 4 + 2) * TT * UU;
    const unsigned* ou3 = (const unsigned*)out + (size_t)(g * 4 + 3) * TT * UU;
    const int b_own = tid >> 4;  // wave-0 update threads
    const int u_own = tid & 15;
    float c_state = 0.0f;
    int epC = 0;

    for (int t = 0; t < TT; ++t) {
      if (t > 0) {
        // Poll ONLY this wave's slice: units [128wv, 128wv+128), 4 batches.
        const size_t roff = (size_t)(t - 1) * UU + 128 * wv + l;
        unsigned v0, v1, v2, v3, v4, v5, v6, v7;
        for (;;) {
          v0 = __hip_atomic_load(ou0 + roff,      __ATOMIC_RELAXED, __HIP_MEMORY_SCOPE_AGENT);
          v1 = __hip_atomic_load(ou0 + roff + 64, __ATOMIC_RELAXED, __HIP_MEMORY_SCOPE_AGENT);
          v2 = __hip_atomic_load(ou1 + roff,      __ATOMIC_RELAXED, __HIP_MEMORY_SCOPE_AGENT);
          v3 = __hip_atomic_load(ou1 + roff + 64, __ATOMIC_RELAXED, __HIP_MEMORY_SCOPE_AGENT);
          v4 = __hip_atomic_load(ou2 + roff,      __ATOMIC_RELAXED, __HIP_MEMORY_SCOPE_AGENT);
          v5 = __hip_atomic_load(ou2 + roff + 64, __ATOMIC_RELAXED, __HIP_MEMORY_SCOPE_AGENT);
          v6 = __hip_atomic_load(ou3 + roff,      __ATOMIC_RELAXED, __HIP_MEMORY_SCOPE_AGENT);
          v7 = __hip_atomic_load(ou3 + roff + 64, __ATOMIC_RELAXED, __HIP_MEMORY_SCOPE_AGENT);
          int ok = (v0 != SENT) & (v1 != SENT) & (v2 != SENT) & (v3 != SENT) &
                   (v4 != SENT) & (v5 != SENT) & (v6 != SENT) & (v7 != SENT);
          if (__all(ok)) break;
          __builtin_amdgcn_s_sleep(1);
        }
        // Stage this wave's slice (only this wave reads it back).
        const int ub = 128 * wv + l;
        LH[0][ub]      = __uint_as_float(v0);
        LH[0][ub + 64] = __uint_as_float(v1);
        LH[1][ub]      = __uint_as_float(v2);
        LH[1][ub + 64] = __uint_as_float(v3);
        LH[2][ub]      = __uint_as_float(v4);
        LH[2][ub + 64] = __uint_as_float(v5);
        LH[3][ub]      = __uint_as_float(v6);
        LH[3][ub + 64] = __uint_as_float(v7);
        asm volatile("s_waitcnt lgkmcnt(0)" ::: "memory");
        __builtin_amdgcn_sched_barrier(0);
        // Dot immediately -- no cross-wave barrier (inputs are wave-local).
        __builtin_amdgcn_s_setprio(1);
        float a00,a01,a10,a11,a20,a21,a30,a31;
        dot64x2_4(&LH[0][o * 64], &LH[1][o * 64], &LH[2][o * 64], &LH[3][o * 64],
                  W, a00,a01,a10,a11,a20,a21,a30,a31);
        const int p = t & 1;
        *(float2*)&LR[p][o][0][col0] = make_float2(a00, a01);
        *(float2*)&LR[p][o][1][col0] = make_float2(a10, a11);
        *(float2*)&LR[p][o][2][col0] = make_float2(a20, a21);
        *(float2*)&LR[p][o][3][col0] = make_float2(a30, a31);
        __builtin_amdgcn_s_setprio(0);
      }
      wavebar<false>(&cCRITbar, epC);  // B2: all LR partials complete
      if (tid < 64) {
        // xz ring slot t must be produced (xz normally runs ahead -> no spin)
        while (__hip_atomic_load(&cXZdone, __ATOMIC_RELAXED,
                                 __HIP_MEMORY_SCOPE_WORKGROUP) < t + 1) {
        }
        asm volatile("" ::: "memory");
        const int s = t & (RDEPTH - 1);
        float s0 = RING[s][b_own][u_own +  0] + LB[u_own +  0];
        float s1 = RING[s][b_own][u_own + 16] + LB[u_own + 16];
        float s2 = RING[s][b_own][u_own + 32] + LB[u_own + 32];
        float s3 = RING[s][b_own][u_own + 48] + LB[u_own + 48];
        if (t > 0) {
          const int p = t & 1;
#pragma unroll
          for (int oo = 0; oo < 8; ++oo) {
            s0 += LR[p][oo][b_own][u_own +  0];
            s1 += LR[p][oo][b_own][u_own + 16];
            s2 += LR[p][oo][b_own][u_own + 32];
            s3 += LR[p][oo][b_own][u_own + 48];
          }
        }
        float gi = hsig(s0);
        float gf = hsig(s1);
        float gc = tanh_fast(s2);
        float go = hsig(s3);
        c_state = gf * c_state + gi * gc;
        float h = go * tanh_fast(c_state);
        __hip_atomic_store(
            out + ((size_t)(g * 4 + b_own) * TT + t) * UU + w * 16 + u_own, h,
            __ATOMIC_RELAXED, __HIP_MEMORY_SCOPE_AGENT);
      }
      if (tid == 0) {
        asm volatile("s_waitcnt lgkmcnt(0)" ::: "memory");
        __hip_atomic_fetch_add(&cCRITdone, 1, __ATOMIC_RELAXED,
                               __HIP_MEMORY_SCOPE_WORKGROUP);
      }
    }
  } else {
    // ---------------- xz pipeline: waves 4-7 (free-running) ----------------
    const float* xb0 = x + (size_t)(g * 4 + 0) * TT * DD + o * 64;
    const float* xb1 = x + (size_t)(g * 4 + 1) * TT * DD + o * 64;
    const float* xb2 = x + (size_t)(g * 4 + 2) * TT * DD + o * 64;
    const float* xb3 = x + (size_t)(g * 4 + 3) * TT * DD + o * 64;
    int epX = 0;

    for (int t = 0; t < TT; ++t) {
      size_t off = (size_t)t * DD;
      float a00,a01,a10,a11,a20,a21,a30,a31;
      dot64x2_4(xb0 + off, xb1 + off, xb2 + off, xb3 + off, W,
                a00,a01,a10,a11,a20,a21,a30,a31);
      *(float2*)&LX[o][0][col0] = make_float2(a00, a01);
      *(float2*)&LX[o][1][col0] = make_float2(a10, a11);
      *(float2*)&LX[o][2][col0] = make_float2(a20, a21);
      *(float2*)&LX[o][3][col0] = make_float2(a30, a31);
      wavebar<true>(&cXZbar, epX);  // partials visible
      // ring slot t&3 free? (consumed when cCRITdone >= t-RDEPTH+1)
      if (t >= RDEPTH) {
        while (__hip_atomic_load(&cCRITdone, __ATOMIC_RELAXED,
                                 __HIP_MEMORY_SCOPE_WORKGROUP) < t - RDEPTH + 1) {
          __builtin_amdgcn_s_sleep(1);
        }
        asm volatile("" ::: "memory");
      }
      {
        const int b2 = idx >> 6, c3 = idx & 63;
        float ssum = 0.f;
#pragma unroll
        for (int oo = 0; oo < 8; ++oo) ssum += LX[oo][b2][c3];
        RING[t & (RDEPTH - 1)][b2][c3] = ssum;
      }
      wavebar<true>(&cXZbar, epX);  // reduce complete (also guards LX overwrite)
      if (idx == 0) {
        asm volatile("s_waitcnt lgkmcnt(0)" ::: "memory");
        __hip_atomic_fetch_add(&cXZdone, 1, __ATOMIC_RELAXED,
                               __HIP_MEMORY_SCOPE_WORKGROUP);
      }
    }
  }
}

extern "C" void kernel_launch(void* const* d_in, const int* in_sizes, int n_in,
                              void* d_out, int out_size, void* d_ws, size_t ws_size,
                              hipStream_t stream) {
  const float* x    = (const float*)d_in[0];
  const float* Wk   = (const float*)d_in[1];
  const float* Wr   = (const float*)d_in[2];
  const float* bias = (const float*)d_in[3];
  float* out = (float*)d_out;

  // Sentinel-fill the h history (graph-capturable async memset).
  hipMemsetAsync(out, 0xFF, (size_t)out_size * sizeof(float), stream);
  lstm_persistent<<<256, 512, 0, stream>>>(x, Wk, Wr, bias, out);
}